// Round 1
// baseline (88.155 us; speedup 1.0000x reference)
//
#include <hip/hip_runtime.h>
#include <math.h>

#define BB 128
#define KK 2048
#define NN 4
#define CC 64
#define DD 3
#define THREADS 256

// One block per batch element.
__global__ void __launch_bounds__(THREADS)
crit_main(const float* __restrict__ loc_out, const float* __restrict__ obj_logit,
          const float* __restrict__ cls_logit, const float* __restrict__ gt_loc,
          const float* __restrict__ gt_cls, float* __restrict__ ws)
{
    __shared__ float cost[NN][KK];       // 32 KB
    __shared__ float s_vt[NN][DD];
    __shared__ float s_pos[NN];
    __shared__ int   s_cls[NN];
    __shared__ float r_val[THREADS];
    __shared__ int   r_idx[THREADS];
    __shared__ float cand_val[NN][NN];
    __shared__ int   cand_idx[NN][NN];
    __shared__ int   s_pred[NN];

    const int b = blockIdx.x;
    const int tid = threadIdx.x;

    // Per-GT setup: normalized gt vector, target class (one-hot argmax), pos_cnt.
    if (tid < NN) {
        const int n = tid;
        float g0 = gt_loc[(b*NN+n)*DD+0];
        float g1 = gt_loc[(b*NN+n)*DD+1];
        float g2 = gt_loc[(b*NN+n)*DD+2];
        float nrm = fmaxf(sqrtf(g0*g0 + g1*g1 + g2*g2), 1e-8f);
        s_vt[n][0] = g0/nrm; s_vt[n][1] = g1/nrm; s_vt[n][2] = g2/nrm;
        int ci = 0; float bestv = -1.f; float psum = 0.f;
        for (int c = 0; c < CC; ++c) {
            float v = gt_cls[(b*NN+n)*CC + c];
            psum += v;
            if (v > bestv) { bestv = v; ci = c; }
        }
        s_cls[n] = ci;
        s_pos[n] = fmaxf(psum, 1.f);
    }
    __syncthreads();

    // Cost matrix + obj base term.
    float obj_base = 0.f;
    for (int k = tid; k < KK; k += THREADS) {
        float l0 = loc_out[((size_t)b*KK+k)*DD+0];
        float l1 = loc_out[((size_t)b*KK+k)*DD+1];
        float l2 = loc_out[((size_t)b*KK+k)*DD+2];
        float nrm = fmaxf(sqrtf(l0*l0 + l1*l1 + l2*l2), 1e-8f);
        float v0 = l0/nrm, v1 = l1/nrm, v2 = l2/nrm;
        float x = obj_logit[b*KK+k];
        obj_base += fmaxf(x, 0.f) + log1pf(expf(-fabsf(x)));
        float oc = -0.1f * (1.f / (1.f + expf(-x)));   // OBJ_CW * obj_cost
        #pragma unroll
        for (int n = 0; n < NN; ++n) {
            float cosv = v0*s_vt[n][0] + v1*s_vt[n][1] + v2*s_vt[n][2];
            cosv = fminf(fmaxf(cosv, -1.f + 1e-6f), 1.f - 1e-6f);
            float loc_c = acosf(cosv) * 0.31830988618379067f;   // /pi
            float z = cls_logit[((size_t)b*KK+k)*CC + s_cls[n]];
            // focal_pos = ALPHA * softplus(-z) * sigmoid(-z)^2
            float sp = (z > 0.f) ? log1pf(expf(-z)) : (-z + log1pf(expf(z)));
            float sn = 1.f / (1.f + expf(z));                   // sigmoid(-z)
            float fp = 0.25f * sp * sn * sn;
            cost[n][k] = loc_c + 0.25f*(fp / s_pos[n]) + oc;
        }
    }
    __syncthreads();

    // Top-4 smallest per GT row via 4 masked argmin rounds each.
    for (int n = 0; n < NN; ++n) {
        for (int r = 0; r < NN; ++r) {
            float bv = INFINITY; int bi = -1;
            for (int k = tid; k < KK; k += THREADS) {
                float v = cost[n][k];
                if (v < bv) { bv = v; bi = k; }
            }
            r_val[tid] = bv; r_idx[tid] = bi;
            __syncthreads();
            for (int s = THREADS/2; s > 0; s >>= 1) {
                if (tid < s) {
                    float ov = r_val[tid+s]; int oi = r_idx[tid+s];
                    if (ov < r_val[tid] ||
                        (ov == r_val[tid] && oi >= 0 && (r_idx[tid] < 0 || oi < r_idx[tid]))) {
                        r_val[tid] = ov; r_idx[tid] = oi;
                    }
                }
                __syncthreads();
            }
            if (tid == 0) {
                cand_val[n][r] = r_val[0];
                cand_idx[n][r] = r_idx[0];
                cost[n][r_idx[0]] = INFINITY;   // mask for next round
            }
            __syncthreads();
        }
    }

    // Brute-force assignment: each row restricted to its own top-4 (exact; see theory).
    if (tid == 0) {
        float bestT = INFINITY;
        int bp0 = cand_idx[0][0], bp1 = cand_idx[1][1&3], bp2 = cand_idx[2][2&3], bp3 = cand_idx[3][3&3];
        for (int a0 = 0; a0 < NN; ++a0)
        for (int a1 = 0; a1 < NN; ++a1)
        for (int a2 = 0; a2 < NN; ++a2)
        for (int a3 = 0; a3 < NN; ++a3) {
            int c0 = cand_idx[0][a0], c1 = cand_idx[1][a1];
            int c2 = cand_idx[2][a2], c3 = cand_idx[3][a3];
            if (c0==c1 || c0==c2 || c0==c3 || c1==c2 || c1==c3 || c2==c3) continue;
            float t = cand_val[0][a0] + cand_val[1][a1] + cand_val[2][a2] + cand_val[3][a3];
            if (t < bestT) { bestT = t; bp0=c0; bp1=c1; bp2=c2; bp3=c3; }
        }
        s_pred[0]=bp0; s_pred[1]=bp1; s_pred[2]=bp2; s_pred[3]=bp3;
    }
    __syncthreads();

    // obj partial: tree-sum base term, subtract matched logits.
    r_val[tid] = obj_base;
    __syncthreads();
    for (int s = THREADS/2; s > 0; s >>= 1) {
        if (tid < s) r_val[tid] += r_val[tid+s];
        __syncthreads();
    }
    if (tid == 0) {
        float om = r_val[0];
        for (int n = 0; n < NN; ++n) om -= obj_logit[b*KK + s_pred[n]];
        ws[b*3+2] = om;
        // loc partial (12 terms)
        float s = 0.f;
        for (int n = 0; n < NN; ++n)
            for (int d = 0; d < DD; ++d) {
                float diff = loc_out[((size_t)b*KK + s_pred[n])*DD + d] - gt_loc[(b*NN+n)*DD + d];
                s += diff*diff;
            }
        ws[b*3+0] = s;
    }
    __syncthreads();

    // cls partial: 256 threads = 4 GT x 64 classes, focal BCE.
    {
        int n = tid >> 6, c = tid & 63;
        float z = cls_logit[((size_t)b*KK + s_pred[n])*CC + c];
        float tgt = gt_cls[(b*NN+n)*CC + c];
        float p  = 1.f / (1.f + expf(-z));
        float ce = fmaxf(z, 0.f) - z*tgt + log1pf(expf(-fabsf(z)));
        float pt = p*tgt + (1.f-p)*(1.f-tgt);
        float at = 0.25f*tgt + 0.75f*(1.f-tgt);
        float om1 = 1.f - pt;
        r_val[tid] = at * ce * om1 * om1;
    }
    __syncthreads();
    for (int s = THREADS/2; s > 0; s >>= 1) {
        if (tid < s) r_val[tid] += r_val[tid+s];
        __syncthreads();
    }
    if (tid == 0) ws[b*3+1] = r_val[0];
}

// Deterministic final reduction over the 128 per-batch partials.
__global__ void __launch_bounds__(BB)
crit_final(const float* __restrict__ ws, float* __restrict__ out)
{
    __shared__ float sl[BB], sc[BB], so[BB];
    int t = threadIdx.x;
    sl[t] = ws[t*3+0]; sc[t] = ws[t*3+1]; so[t] = ws[t*3+2];
    __syncthreads();
    for (int s = BB/2; s > 0; s >>= 1) {
        if (t < s) { sl[t]+=sl[t+s]; sc[t]+=sc[t+s]; so[t]+=so[t+s]; }
        __syncthreads();
    }
    if (t == 0) {
        out[0] = sl[0] / (float)(BB*NN*DD)
               + sc[0] / (float)(BB*NN*CC)
               + so[0] / (float)(BB*KK);
    }
}

extern "C" void kernel_launch(void* const* d_in, const int* in_sizes, int n_in,
                              void* d_out, int out_size, void* d_ws, size_t ws_size,
                              hipStream_t stream) {
    const float* loc_out   = (const float*)d_in[0];
    const float* obj_logit = (const float*)d_in[1];
    const float* cls_logit = (const float*)d_in[2];
    const float* gt_loc    = (const float*)d_in[3];
    const float* gt_cls    = (const float*)d_in[4];
    float* ws  = (float*)d_ws;
    float* out = (float*)d_out;

    hipLaunchKernelGGL(crit_main, dim3(BB), dim3(THREADS), 0, stream,
                       loc_out, obj_logit, cls_logit, gt_loc, gt_cls, ws);
    hipLaunchKernelGGL(crit_final, dim3(1), dim3(BB), 0, stream, ws, out);
}

// Round 2
// 85.950 us; speedup vs baseline: 1.0257x; 1.0257x over previous
//
#include <hip/hip_runtime.h>
#include <math.h>

#define BB 128
#define KK 2048
#define NN 4
#define CC 64
#define DD 3
#define SL 8            // K-slices per batch
#define KS (KK/SL)      // 256 k per slice
#define THREADS 256

// ws layout (float words):
// [OFF_CVAL, +B*SL*NN*NN)  candidate values  [B][SL][row][4]
// [OFF_CIDX, +B*SL*NN*NN)  candidate indices (int bits)
// [OFF_OBJ,  +B*SL)        obj base partial per (b,slice)
// [OFF_PART, +B*3)         per-batch loss partials {loc,cls,obj}
#define OFF_CVAL 0
#define OFF_CIDX (BB*SL*NN*NN)
#define OFF_OBJ  (2*BB*SL*NN*NN)
#define OFF_PART (OFF_OBJ + BB*SL)

// ---------------- Kernel A: cost + per-slice top-4 per GT row ----------------
__global__ void __launch_bounds__(THREADS)
crit_cost(const float* __restrict__ loc_out, const float* __restrict__ obj_logit,
          const float* __restrict__ cls_logit, const float* __restrict__ gt_loc,
          const float* __restrict__ gt_cls, float* __restrict__ ws)
{
    __shared__ float s_vt[NN][DD];
    __shared__ float s_pos[NN];
    __shared__ int   s_cls[NN];
    __shared__ float cost[NN][KS];     // 4 KB
    __shared__ float obj_s[4];

    const int sl  = blockIdx.x;
    const int b   = blockIdx.y;
    const int tid = threadIdx.x;

    if (tid < NN) {
        const int n = tid;
        float g0 = gt_loc[(b*NN+n)*DD+0];
        float g1 = gt_loc[(b*NN+n)*DD+1];
        float g2 = gt_loc[(b*NN+n)*DD+2];
        float nrm = fmaxf(sqrtf(g0*g0 + g1*g1 + g2*g2), 1e-8f);
        s_vt[n][0] = g0/nrm; s_vt[n][1] = g1/nrm; s_vt[n][2] = g2/nrm;
        int ci = 0; float bestv = -1.f; float psum = 0.f;
        for (int c = 0; c < CC; ++c) {
            float v = gt_cls[(b*NN+n)*CC + c];
            psum += v;
            if (v > bestv) { bestv = v; ci = c; }
        }
        s_cls[n] = ci;
        s_pos[n] = fmaxf(psum, 1.f);
    }
    __syncthreads();

    const int k = sl*KS + tid;
    float l0 = loc_out[((size_t)b*KK+k)*DD+0];
    float l1 = loc_out[((size_t)b*KK+k)*DD+1];
    float l2 = loc_out[((size_t)b*KK+k)*DD+2];
    float nrm = fmaxf(sqrtf(l0*l0 + l1*l1 + l2*l2), 1e-8f);
    float v0 = l0/nrm, v1 = l1/nrm, v2 = l2/nrm;
    float x = obj_logit[b*KK+k];
    float obj_base = fmaxf(x, 0.f) + log1pf(expf(-fabsf(x)));
    float oc = -0.1f * (1.f / (1.f + expf(-x)));       // OBJ_CW * obj_cost
    #pragma unroll
    for (int n = 0; n < NN; ++n) {
        float cosv = v0*s_vt[n][0] + v1*s_vt[n][1] + v2*s_vt[n][2];
        cosv = fminf(fmaxf(cosv, -1.f + 1e-6f), 1.f - 1e-6f);
        float loc_c = acosf(cosv) * 0.31830988618379067f;
        float z = cls_logit[((size_t)b*KK+k)*CC + s_cls[n]];
        float sp = (z > 0.f) ? log1pf(expf(-z)) : (-z + log1pf(expf(z)));  // softplus(-z)
        float sn = 1.f / (1.f + expf(z));                                   // sigmoid(-z)
        float fp = 0.25f * sp * sn * sn;
        cost[n][tid] = loc_c + 0.25f*(fp / s_pos[n]) + oc;
    }

    // obj partial: wave shfl-sum, then 4-wave combine by thread 0.
    float osum = obj_base;
    #pragma unroll
    for (int off = 32; off > 0; off >>= 1) osum += __shfl_xor(osum, off, 64);
    if ((tid & 63) == 0) obj_s[tid >> 6] = osum;
    __syncthreads();   // cost[][] + obj_s visible

    // Wave w selects top-4 of row w across KS=256 values; wave-synchronous.
    const int w = tid >> 6, lane = tid & 63;
    float vv[4]; int gi[4];
    #pragma unroll
    for (int j = 0; j < 4; ++j) {
        vv[j] = cost[w][lane + 64*j];
        gi[j] = sl*KS + lane + 64*j;
    }
    float cr_val[NN]; int cr_idx[NN];
    #pragma unroll
    for (int r = 0; r < NN; ++r) {
        float bv = vv[0]; int bi = gi[0];
        #pragma unroll
        for (int j = 1; j < 4; ++j)
            if (vv[j] < bv || (vv[j] == bv && gi[j] < bi)) { bv = vv[j]; bi = gi[j]; }
        #pragma unroll
        for (int off = 32; off > 0; off >>= 1) {
            float ov = __shfl_xor(bv, off, 64);
            int   oi = __shfl_xor(bi, off, 64);
            if (ov < bv || (ov == bv && oi < bi)) { bv = ov; bi = oi; }
        }
        cr_val[r] = bv; cr_idx[r] = bi;
        #pragma unroll
        for (int j = 0; j < 4; ++j) if (gi[j] == bi) vv[j] = INFINITY;
    }
    if (lane == 0) {
        int base = ((b*SL + sl)*NN + w)*NN;
        int* wsi = (int*)ws;
        #pragma unroll
        for (int r = 0; r < NN; ++r) {
            ws[OFF_CVAL + base + r]  = cr_val[r];
            wsi[OFF_CIDX + base + r] = cr_idx[r];
        }
    }
    if (tid == 0)
        ws[OFF_OBJ + b*SL + sl] = obj_s[0] + obj_s[1] + obj_s[2] + obj_s[3];
}

// ---------------- Kernel B: merge candidates, assign, loss partials ----------------
__global__ void __launch_bounds__(THREADS)
crit_match(const float* __restrict__ loc_out, const float* __restrict__ obj_logit,
           const float* __restrict__ cls_logit, const float* __restrict__ gt_loc,
           const float* __restrict__ gt_cls, float* __restrict__ ws)
{
    __shared__ float cand_val[NN][NN];
    __shared__ int   cand_idx[NN][NN];
    __shared__ int   s_pred[NN];
    __shared__ float red[THREADS];

    const int b = blockIdx.x, tid = threadIdx.x;
    const int* wsi = (const int*)ws;

    if (tid < NN) {
        const int n = tid;
        float tv[NN] = {INFINITY, INFINITY, INFINITY, INFINITY};
        int   ti[NN] = {-1, -1, -1, -1};
        for (int sl = 0; sl < SL; ++sl) {
            int base = ((b*SL + sl)*NN + n)*NN;
            for (int r = 0; r < NN; ++r) {
                float v = ws[OFF_CVAL + base + r];
                int   i = wsi[OFF_CIDX + base + r];
                for (int t = 0; t < NN; ++t) {
                    if (v < tv[t] || (v == tv[t] && i < ti[t])) {
                        for (int u = NN-1; u > t; --u) { tv[u] = tv[u-1]; ti[u] = ti[u-1]; }
                        tv[t] = v; ti[t] = i;
                        break;
                    }
                }
            }
        }
        for (int r = 0; r < NN; ++r) { cand_val[n][r] = tv[r]; cand_idx[n][r] = ti[r]; }
    }
    __syncthreads();

    if (tid == 0) {
        float bestT = INFINITY;
        int bp0 = cand_idx[0][0], bp1 = cand_idx[1][0], bp2 = cand_idx[2][0], bp3 = cand_idx[3][0];
        for (int a0 = 0; a0 < NN; ++a0)
        for (int a1 = 0; a1 < NN; ++a1)
        for (int a2 = 0; a2 < NN; ++a2)
        for (int a3 = 0; a3 < NN; ++a3) {
            int c0 = cand_idx[0][a0], c1 = cand_idx[1][a1];
            int c2 = cand_idx[2][a2], c3 = cand_idx[3][a3];
            if (c0==c1 || c0==c2 || c0==c3 || c1==c2 || c1==c3 || c2==c3) continue;
            float t = cand_val[0][a0] + cand_val[1][a1] + cand_val[2][a2] + cand_val[3][a3];
            if (t < bestT) { bestT = t; bp0=c0; bp1=c1; bp2=c2; bp3=c3; }
        }
        s_pred[0]=bp0; s_pred[1]=bp1; s_pred[2]=bp2; s_pred[3]=bp3;

        // obj partial
        float om = 0.f;
        for (int sl = 0; sl < SL; ++sl) om += ws[OFF_OBJ + b*SL + sl];
        om -= obj_logit[b*KK + bp0] + obj_logit[b*KK + bp1]
            + obj_logit[b*KK + bp2] + obj_logit[b*KK + bp3];
        ws[OFF_PART + b*3 + 2] = om;

        // loc partial (12 terms)
        int bp[NN] = {bp0, bp1, bp2, bp3};
        float s = 0.f;
        for (int n = 0; n < NN; ++n)
            for (int d = 0; d < DD; ++d) {
                float diff = loc_out[((size_t)b*KK + bp[n])*DD + d] - gt_loc[(b*NN+n)*DD + d];
                s += diff*diff;
            }
        ws[OFF_PART + b*3 + 0] = s;
    }
    __syncthreads();

    // cls partial: 256 threads = 4 rows x 64 classes
    {
        int n = tid >> 6, c = tid & 63;
        float z = cls_logit[((size_t)b*KK + s_pred[n])*CC + c];
        float tgt = gt_cls[(b*NN+n)*CC + c];
        float p  = 1.f / (1.f + expf(-z));
        float ce = fmaxf(z, 0.f) - z*tgt + log1pf(expf(-fabsf(z)));
        float pt = p*tgt + (1.f-p)*(1.f-tgt);
        float at = 0.25f*tgt + 0.75f*(1.f-tgt);
        float om1 = 1.f - pt;
        red[tid] = at * ce * om1 * om1;
    }
    __syncthreads();
    for (int s = THREADS/2; s > 0; s >>= 1) {
        if (tid < s) red[tid] += red[tid+s];
        __syncthreads();
    }
    if (tid == 0) ws[OFF_PART + b*3 + 1] = red[0];
}

// ---------------- Kernel C: deterministic final reduction ----------------
__global__ void __launch_bounds__(BB)
crit_final(const float* __restrict__ ws, float* __restrict__ out)
{
    __shared__ float sl_[BB], sc_[BB], so_[BB];
    int t = threadIdx.x;
    sl_[t] = ws[OFF_PART + t*3+0];
    sc_[t] = ws[OFF_PART + t*3+1];
    so_[t] = ws[OFF_PART + t*3+2];
    __syncthreads();
    for (int s = BB/2; s > 0; s >>= 1) {
        if (t < s) { sl_[t]+=sl_[t+s]; sc_[t]+=sc_[t+s]; so_[t]+=so_[t+s]; }
        __syncthreads();
    }
    if (t == 0) {
        out[0] = sl_[0] / (float)(BB*NN*DD)
               + sc_[0] / (float)(BB*NN*CC)
               + so_[0] / (float)(BB*KK);
    }
}

extern "C" void kernel_launch(void* const* d_in, const int* in_sizes, int n_in,
                              void* d_out, int out_size, void* d_ws, size_t ws_size,
                              hipStream_t stream) {
    const float* loc_out   = (const float*)d_in[0];
    const float* obj_logit = (const float*)d_in[1];
    const float* cls_logit = (const float*)d_in[2];
    const float* gt_loc    = (const float*)d_in[3];
    const float* gt_cls    = (const float*)d_in[4];
    float* ws  = (float*)d_ws;
    float* out = (float*)d_out;

    hipLaunchKernelGGL(crit_cost, dim3(SL, BB), dim3(THREADS), 0, stream,
                       loc_out, obj_logit, cls_logit, gt_loc, gt_cls, ws);
    hipLaunchKernelGGL(crit_match, dim3(BB), dim3(THREADS), 0, stream,
                       loc_out, obj_logit, cls_logit, gt_loc, gt_cls, ws);
    hipLaunchKernelGGL(crit_final, dim3(1), dim3(BB), 0, stream, ws, out);
}

// Round 3
// 35.474 us; speedup vs baseline: 2.4851x; 2.4229x over previous
//
#include <hip/hip_runtime.h>
#include <math.h>
#include <limits.h>

#define BB 128
#define KK 2048
#define NN 4
#define CC 64
#define DD 3
#define SL 8            // K-slices per batch
#define KS (KK/SL)      // 256 k per slice
#define THREADS 256

// ws layout (float words):
#define OFF_CVAL 0
#define OFF_CIDX (BB*SL*NN*NN)
#define OFF_OBJ  (2*BB*SL*NN*NN)
#define OFF_PART (OFF_OBJ + BB*SL)

// ---------------- Kernel A: cost + per-slice top-4 per GT row ----------------
__global__ void __launch_bounds__(THREADS)
crit_cost(const float* __restrict__ loc_out, const float* __restrict__ obj_logit,
          const float* __restrict__ cls_logit, const float* __restrict__ gt_loc,
          const float* __restrict__ gt_cls, float* __restrict__ ws)
{
    __shared__ float s_vt[NN][DD];
    __shared__ float s_pos[NN];
    __shared__ int   s_cls[NN];
    __shared__ float cost[NN][KS];     // 4 KB
    __shared__ float obj_s[4];

    const int sl  = blockIdx.x;
    const int b   = blockIdx.y;
    const int tid = threadIdx.x;
    const int w   = tid >> 6, lane = tid & 63;

    // Wave-parallel GT setup: wave w handles row w; lane = class.
    {
        float v = gt_cls[(b*NN+w)*CC + lane];
        float psum = v;
        float bv = v; int bc = lane;
        #pragma unroll
        for (int off = 32; off > 0; off >>= 1) {
            psum += __shfl_xor(psum, off, 64);
            float ov = __shfl_xor(bv, off, 64);
            int   oc = __shfl_xor(bc, off, 64);
            if (ov > bv || (ov == bv && oc < bc)) { bv = ov; bc = oc; }
        }
        if (lane == 0) {
            s_cls[w] = bc;
            s_pos[w] = fmaxf(psum, 1.f);
            float g0 = gt_loc[(b*NN+w)*DD+0];
            float g1 = gt_loc[(b*NN+w)*DD+1];
            float g2 = gt_loc[(b*NN+w)*DD+2];
            float nrm = fmaxf(sqrtf(g0*g0 + g1*g1 + g2*g2), 1e-8f);
            s_vt[w][0] = g0/nrm; s_vt[w][1] = g1/nrm; s_vt[w][2] = g2/nrm;
        }
    }
    __syncthreads();

    const int k = sl*KS + tid;
    float l0 = loc_out[((size_t)b*KK+k)*DD+0];
    float l1 = loc_out[((size_t)b*KK+k)*DD+1];
    float l2 = loc_out[((size_t)b*KK+k)*DD+2];
    float nrm = fmaxf(sqrtf(l0*l0 + l1*l1 + l2*l2), 1e-8f);
    float v0 = l0/nrm, v1 = l1/nrm, v2 = l2/nrm;
    float x = obj_logit[b*KK+k];
    float obj_base = fmaxf(x, 0.f) + log1pf(expf(-fabsf(x)));
    float oc = -0.1f * (1.f / (1.f + expf(-x)));       // OBJ_CW * obj_cost
    #pragma unroll
    for (int n = 0; n < NN; ++n) {
        float cosv = v0*s_vt[n][0] + v1*s_vt[n][1] + v2*s_vt[n][2];
        cosv = fminf(fmaxf(cosv, -1.f + 1e-6f), 1.f - 1e-6f);
        float loc_c = acosf(cosv) * 0.31830988618379067f;
        float z = cls_logit[((size_t)b*KK+k)*CC + s_cls[n]];
        float sp = (z > 0.f) ? log1pf(expf(-z)) : (-z + log1pf(expf(z)));  // softplus(-z)
        float sn = 1.f / (1.f + expf(z));                                   // sigmoid(-z)
        float fp = 0.25f * sp * sn * sn;
        cost[n][tid] = loc_c + 0.25f*(fp / s_pos[n]) + oc;
    }

    // obj partial: wave shfl-sum, 4-wave combine.
    float osum = obj_base;
    #pragma unroll
    for (int off = 32; off > 0; off >>= 1) osum += __shfl_xor(osum, off, 64);
    if (lane == 0) obj_s[w] = osum;
    __syncthreads();   // cost[][] + obj_s visible

    // Wave w selects top-4 of row w across KS=256 values (wave-synchronous).
    float vv[4]; int gi[4];
    #pragma unroll
    for (int j = 0; j < 4; ++j) {
        vv[j] = cost[w][lane + 64*j];
        gi[j] = sl*KS + lane + 64*j;
    }
    float cr_val[NN]; int cr_idx[NN];
    #pragma unroll
    for (int r = 0; r < NN; ++r) {
        float bv = vv[0]; int bi = gi[0];
        #pragma unroll
        for (int j = 1; j < 4; ++j)
            if (vv[j] < bv || (vv[j] == bv && gi[j] < bi)) { bv = vv[j]; bi = gi[j]; }
        #pragma unroll
        for (int off = 32; off > 0; off >>= 1) {
            float ov = __shfl_xor(bv, off, 64);
            int   oi = __shfl_xor(bi, off, 64);
            if (ov < bv || (ov == bv && oi < bi)) { bv = ov; bi = oi; }
        }
        cr_val[r] = bv; cr_idx[r] = bi;
        #pragma unroll
        for (int j = 0; j < 4; ++j) if (gi[j] == bi) vv[j] = INFINITY;
    }
    if (lane == 0) {
        int base = ((b*SL + sl)*NN + w)*NN;
        int* wsi = (int*)ws;
        #pragma unroll
        for (int r = 0; r < NN; ++r) {
            ws[OFF_CVAL + base + r]  = cr_val[r];
            wsi[OFF_CIDX + base + r] = cr_idx[r];
        }
    }
    if (tid == 0)
        ws[OFF_OBJ + b*SL + sl] = obj_s[0] + obj_s[1] + obj_s[2] + obj_s[3];
}

// ---------------- Kernel B: merge candidates, assign, loss partials ----------------
__global__ void __launch_bounds__(THREADS)
crit_match(const float* __restrict__ loc_out, const float* __restrict__ obj_logit,
           const float* __restrict__ cls_logit, const float* __restrict__ gt_loc,
           const float* __restrict__ gt_cls, float* __restrict__ ws)
{
    __shared__ float cand_val[NN][NN];
    __shared__ int   cand_idx[NN][NN];
    __shared__ int   s_pred[NN];
    __shared__ float s_best[4];
    __shared__ int   s_bestc[4];
    __shared__ float red[4];

    const int b = blockIdx.x, tid = threadIdx.x;
    const int w = tid >> 6, lane = tid & 63;
    const int* wsi = (const int*)ws;

    // Merge: wave w holds the 32 candidates of row w in lanes 0..31.
    {
        float v = INFINITY; int idx = INT_MAX;
        if (lane < SL*NN) {
            int sl = lane >> 2, r = lane & 3;
            int base = ((b*SL + sl)*NN + w)*NN + r;
            v   = ws[OFF_CVAL + base];
            idx = wsi[OFF_CIDX + base];
        }
        #pragma unroll
        for (int r = 0; r < NN; ++r) {
            float bv = v; int bi = idx;
            #pragma unroll
            for (int off = 32; off > 0; off >>= 1) {
                float ov = __shfl_xor(bv, off, 64);
                int   oi = __shfl_xor(bi, off, 64);
                if (ov < bv || (ov == bv && oi < bi)) { bv = ov; bi = oi; }
            }
            if (lane == 0) { cand_val[w][r] = bv; cand_idx[w][r] = bi; }
            if (idx == bi) v = INFINITY;   // mask winner
        }
    }
    __syncthreads();

    // Brute force: thread tid evaluates combo tid (a0..a3 = 2-bit fields).
    {
        int a0 = (tid >> 6) & 3, a1 = (tid >> 4) & 3, a2 = (tid >> 2) & 3, a3 = tid & 3;
        int c0 = cand_idx[0][a0], c1 = cand_idx[1][a1];
        int c2 = cand_idx[2][a2], c3 = cand_idx[3][a3];
        bool valid = (c0!=c1) & (c0!=c2) & (c0!=c3) & (c1!=c2) & (c1!=c3) & (c2!=c3);
        float t = cand_val[0][a0] + cand_val[1][a1] + cand_val[2][a2] + cand_val[3][a3];
        float bv = valid ? t : INFINITY;
        int   bc = tid;
        #pragma unroll
        for (int off = 32; off > 0; off >>= 1) {
            float ov = __shfl_xor(bv, off, 64);
            int   oc = __shfl_xor(bc, off, 64);
            if (ov < bv || (ov == bv && oc < bc)) { bv = ov; bc = oc; }
        }
        if (lane == 0) { s_best[w] = bv; s_bestc[w] = bc; }
    }
    __syncthreads();

    if (tid == 0) {
        float bv = s_best[0]; int bc = s_bestc[0];
        for (int i = 1; i < 4; ++i)
            if (s_best[i] < bv || (s_best[i] == bv && s_bestc[i] < bc)) { bv = s_best[i]; bc = s_bestc[i]; }
        int a0 = (bc >> 6) & 3, a1 = (bc >> 4) & 3, a2 = (bc >> 2) & 3, a3 = bc & 3;
        s_pred[0] = cand_idx[0][a0]; s_pred[1] = cand_idx[1][a1];
        s_pred[2] = cand_idx[2][a2]; s_pred[3] = cand_idx[3][a3];
    }
    __syncthreads();

    // loc + obj partials on a few parallel lanes of wave 0 (short chains).
    if (tid == 0) {
        float om = 0.f;
        for (int sl = 0; sl < SL; ++sl) om += ws[OFF_OBJ + b*SL + sl];
        for (int n = 0; n < NN; ++n) om -= obj_logit[b*KK + s_pred[n]];
        ws[OFF_PART + b*3 + 2] = om;
        float s = 0.f;
        for (int n = 0; n < NN; ++n)
            for (int d = 0; d < DD; ++d) {
                float diff = loc_out[((size_t)b*KK + s_pred[n])*DD + d] - gt_loc[(b*NN+n)*DD + d];
                s += diff*diff;
            }
        ws[OFF_PART + b*3 + 0] = s;
    }

    // cls partial: 256 threads = 4 rows x 64 classes; shfl-sum + 4-way combine.
    {
        int n = w, c = lane;
        float z = cls_logit[((size_t)b*KK + s_pred[n])*CC + c];
        float tgt = gt_cls[(b*NN+n)*CC + c];
        float p  = 1.f / (1.f + expf(-z));
        float ce = fmaxf(z, 0.f) - z*tgt + log1pf(expf(-fabsf(z)));
        float pt = p*tgt + (1.f-p)*(1.f-tgt);
        float at = 0.25f*tgt + 0.75f*(1.f-tgt);
        float om1 = 1.f - pt;
        float r = at * ce * om1 * om1;
        #pragma unroll
        for (int off = 32; off > 0; off >>= 1) r += __shfl_xor(r, off, 64);
        if (lane == 0) red[n] = r;
    }
    __syncthreads();
    if (tid == 0) ws[OFF_PART + b*3 + 1] = red[0] + red[1] + red[2] + red[3];
}

// ---------------- Kernel C: deterministic final reduction ----------------
__global__ void __launch_bounds__(BB)
crit_final(const float* __restrict__ ws, float* __restrict__ out)
{
    __shared__ float s2[3][2];
    int t = threadIdx.x;
    int w = t >> 6, lane = t & 63;
    float a = ws[OFF_PART + t*3+0];
    float b = ws[OFF_PART + t*3+1];
    float c = ws[OFF_PART + t*3+2];
    #pragma unroll
    for (int off = 32; off > 0; off >>= 1) {
        a += __shfl_xor(a, off, 64);
        b += __shfl_xor(b, off, 64);
        c += __shfl_xor(c, off, 64);
    }
    if (lane == 0) { s2[0][w] = a; s2[1][w] = b; s2[2][w] = c; }
    __syncthreads();
    if (t == 0) {
        out[0] = (s2[0][0]+s2[0][1]) / (float)(BB*NN*DD)
               + (s2[1][0]+s2[1][1]) / (float)(BB*NN*CC)
               + (s2[2][0]+s2[2][1]) / (float)(BB*KK);
    }
}

extern "C" void kernel_launch(void* const* d_in, const int* in_sizes, int n_in,
                              void* d_out, int out_size, void* d_ws, size_t ws_size,
                              hipStream_t stream) {
    const float* loc_out   = (const float*)d_in[0];
    const float* obj_logit = (const float*)d_in[1];
    const float* cls_logit = (const float*)d_in[2];
    const float* gt_loc    = (const float*)d_in[3];
    const float* gt_cls    = (const float*)d_in[4];
    float* ws  = (float*)d_ws;
    float* out = (float*)d_out;

    hipLaunchKernelGGL(crit_cost, dim3(SL, BB), dim3(THREADS), 0, stream,
                       loc_out, obj_logit, cls_logit, gt_loc, gt_cls, ws);
    hipLaunchKernelGGL(crit_match, dim3(BB), dim3(THREADS), 0, stream,
                       loc_out, obj_logit, cls_logit, gt_loc, gt_cls, ws);
    hipLaunchKernelGGL(crit_final, dim3(1), dim3(BB), 0, stream, ws, out);
}